// Round 2
// 369.776 us; speedup vs baseline: 1.2257x; 1.2257x over previous
//
#include <hip/hip_runtime.h>
#include <stdint.h>

#define LSEQ 1024
#define HDIM 1024
#define DDIM 2048
#define BL 2048
#define NST 16
#define XR 1027          // 3 halo rows (unused, zero-pad region) + 1024 tokens

typedef unsigned short u16;
typedef __attribute__((ext_vector_type(8))) short bf16x8;
typedef __attribute__((ext_vector_type(4))) float f32x4;

static __device__ __forceinline__ float silu_f(float v) { return v / (1.f + __expf(-v)); }
static __device__ __forceinline__ float bf2f(u16 u) {
  union { float f; unsigned int i; } c; c.i = ((unsigned int)u) << 16; return c.f;
}
static __device__ __forceinline__ u16 f2bf(float f) {
  union { float f; unsigned int i; } c; c.f = f;
  unsigned int r = c.i + 0x7fffu + ((c.i >> 16) & 1u);
  return (u16)(r >> 16);
}

// ---------------- cast fp32 -> bf16 (weights, once per launch) ----------------
__global__ __launch_bounds__(256) void k_castw(const float* __restrict__ src,
                                               u16* __restrict__ dst) {
  int idx = blockIdx.x * 256 + threadIdx.x;
  float4 v = ((const float4*)src)[idx];
  ushort4 o;
  o.x = f2bf(v.x); o.y = f2bf(v.y); o.z = f2bf(v.z); o.w = f2bf(v.w);
  ((ushort4*)dst)[idx] = o;
}

// ---------------- per-row rmsnorm scale ----------------
__global__ __launch_bounds__(256) void k_rowscale(const float* __restrict__ inp,
                                                  float* __restrict__ rs) {
  int row = blockIdx.x;
  int t = threadIdx.x;
  float4 xv = *(const float4*)(inp + (size_t)row * HDIM + t * 4);
  float ss = xv.x * xv.x + xv.y * xv.y + xv.z * xv.z + xv.w * xv.w;
  for (int off = 32; off > 0; off >>= 1) ss += __shfl_down(ss, off);
  __shared__ float red[4];
  if ((t & 63) == 0) red[t >> 6] = ss;
  __syncthreads();
  if (t == 0) {
    float tot = red[0] + red[1] + red[2] + red[3];
    rs[row] = rsqrtf(tot * (1.f / HDIM) + 1e-6f);
  }
}

// ---------------- K1: in_proj MFMA GEMM, rmsnorm fused into A staging ----------------
// Full M=2048, N=4096, K=1024. 64x64 tile. Output bf16 xgb [2][XR][4096].
__global__ __launch_bounds__(256) void k_gemm1_mfma(const float* __restrict__ inp,
                                                    const u16* __restrict__ W,
                                                    const float* __restrict__ bias,
                                                    const float* __restrict__ rscale,
                                                    const float* __restrict__ nw,
                                                    u16* __restrict__ xgb) {
  __shared__ u16 Asm[64 * 40];
  __shared__ u16 Wsm[64 * 40];
  int t = threadIdx.x;
  int m0 = blockIdx.y * 64, n0 = blockIdx.x * 64;
  int srow = t >> 2, koff = (t & 3) * 8;
  int gin = m0 + srow;
  const float* Ag = inp + (size_t)gin * HDIM + koff;
  const u16* Wg = W + (size_t)(n0 + srow) * HDIM + koff;
  float scale = rscale[gin];
  int w = t >> 6, lane = t & 63;
  int quad = lane >> 4, mr = lane & 15;
  f32x4 z = {0.f, 0.f, 0.f, 0.f};
  f32x4 acc0 = z, acc1 = z, acc2 = z, acc3 = z;
  const u16* arp = &Asm[(16 * w + mr) * 40 + quad * 8];
  const u16* brp = &Wsm[mr * 40 + quad * 8];
  for (int k0 = 0; k0 < HDIM; k0 += 32) {
    float4 a0 = *(const float4*)(Ag + k0);
    float4 a1 = *(const float4*)(Ag + k0 + 4);
    float4 n0v = *(const float4*)(nw + k0 + koff);
    float4 n1v = *(const float4*)(nw + k0 + koff + 4);
    uint4 wv = *(const uint4*)(Wg + k0);
    ushort4 p0, p1;
    p0.x = f2bf(a0.x * scale * n0v.x); p0.y = f2bf(a0.y * scale * n0v.y);
    p0.z = f2bf(a0.z * scale * n0v.z); p0.w = f2bf(a0.w * scale * n0v.w);
    p1.x = f2bf(a1.x * scale * n1v.x); p1.y = f2bf(a1.y * scale * n1v.y);
    p1.z = f2bf(a1.z * scale * n1v.z); p1.w = f2bf(a1.w * scale * n1v.w);
    __syncthreads();
    *(ushort4*)(&Asm[srow * 40 + koff]) = p0;
    *(ushort4*)(&Asm[srow * 40 + koff + 4]) = p1;
    *(uint4*)(&Wsm[srow * 40 + koff]) = wv;
    __syncthreads();
    bf16x8 af = *(const bf16x8*)arp;
    bf16x8 b0 = *(const bf16x8*)(brp);
    bf16x8 b1 = *(const bf16x8*)(brp + 16 * 40);
    bf16x8 b2 = *(const bf16x8*)(brp + 32 * 40);
    bf16x8 b3 = *(const bf16x8*)(brp + 48 * 40);
    acc0 = __builtin_amdgcn_mfma_f32_16x16x32_bf16(af, b0, acc0, 0, 0, 0);
    acc1 = __builtin_amdgcn_mfma_f32_16x16x32_bf16(af, b1, acc1, 0, 0, 0);
    acc2 = __builtin_amdgcn_mfma_f32_16x16x32_bf16(af, b2, acc2, 0, 0, 0);
    acc3 = __builtin_amdgcn_mfma_f32_16x16x32_bf16(af, b3, acc3, 0, 0, 0);
  }
  f32x4 accs[4] = {acc0, acc1, acc2, acc3};
#pragma unroll
  for (int i = 0; i < 4; i++) {
    int col = n0 + 16 * i + mr;
    float bv = bias[col];
#pragma unroll
    for (int rr2 = 0; rr2 < 4; rr2++) {
      int rr = m0 + 16 * w + quad * 4 + rr2;
      int row = (rr >> 10) * XR + 3 + (rr & 1023);
      xgb[(size_t)row * 4096 + col] = f2bf(accs[i][rr2] + bv);
    }
  }
}

// ---------------- K4: out_proj MFMA GEMM + bias + residual (fp32 out) ----------------
__global__ __launch_bounds__(256) void k_gemm2_mfma(const u16* __restrict__ A,   // yb [2048][2048] bf16
                                                    const u16* __restrict__ W,   // wob [1024][2048] bf16
                                                    const float* __restrict__ bias,
                                                    const float* __restrict__ resid,
                                                    float* __restrict__ out) {
  __shared__ u16 Asm[64 * 40];
  __shared__ u16 Wsm[64 * 40];
  int t = threadIdx.x;
  int m0 = blockIdx.y * 64, n0 = blockIdx.x * 64;
  int srow = t >> 2, koff = (t & 3) * 8;
  const u16* Ag = A + (size_t)(m0 + srow) * DDIM + koff;
  const u16* Wg = W + (size_t)(n0 + srow) * DDIM + koff;
  int w = t >> 6, lane = t & 63;
  int quad = lane >> 4, mr = lane & 15;
  f32x4 z = {0.f, 0.f, 0.f, 0.f};
  f32x4 acc0 = z, acc1 = z, acc2 = z, acc3 = z;
  const u16* arp = &Asm[(16 * w + mr) * 40 + quad * 8];
  const u16* brp = &Wsm[mr * 40 + quad * 8];
  for (int k0 = 0; k0 < DDIM; k0 += 32) {
    uint4 av = *(const uint4*)(Ag + k0);
    uint4 wv = *(const uint4*)(Wg + k0);
    __syncthreads();
    *(uint4*)(&Asm[srow * 40 + koff]) = av;
    *(uint4*)(&Wsm[srow * 40 + koff]) = wv;
    __syncthreads();
    bf16x8 af = *(const bf16x8*)arp;
    bf16x8 b0 = *(const bf16x8*)(brp);
    bf16x8 b1 = *(const bf16x8*)(brp + 16 * 40);
    bf16x8 b2 = *(const bf16x8*)(brp + 32 * 40);
    bf16x8 b3 = *(const bf16x8*)(brp + 48 * 40);
    acc0 = __builtin_amdgcn_mfma_f32_16x16x32_bf16(af, b0, acc0, 0, 0, 0);
    acc1 = __builtin_amdgcn_mfma_f32_16x16x32_bf16(af, b1, acc1, 0, 0, 0);
    acc2 = __builtin_amdgcn_mfma_f32_16x16x32_bf16(af, b2, acc2, 0, 0, 0);
    acc3 = __builtin_amdgcn_mfma_f32_16x16x32_bf16(af, b3, acc3, 0, 0, 0);
  }
  f32x4 accs[4] = {acc0, acc1, acc2, acc3};
#pragma unroll
  for (int i = 0; i < 4; i++) {
    int col = n0 + 16 * i + mr;
    float bv = bias[col];
#pragma unroll
    for (int rr2 = 0; rr2 < 4; rr2++) {
      int gout = m0 + 16 * w + quad * 4 + rr2;
      out[(size_t)gout * HDIM + col] =
          accs[i][rr2] + bv + resid[(size_t)gout * HDIM + col];
    }
  }
}

// ---------------- K2: conv+silu (LDS) then x_proj; token-major proj[BL][96] ----------------
__global__ __launch_bounds__(256) void k_xprojc(const u16* __restrict__ xgb,
                                                const float* __restrict__ cw,
                                                const float* __restrict__ cb,
                                                const float* __restrict__ w,
                                                const float* __restrict__ b,
                                                float* __restrict__ proj) {
  __shared__ float row[DDIM];
  int bb = blockIdx.x >> 10, l = blockIdx.x & 1023;
  int t = threadIdx.x;
  int d = t * 8;
  float acc[8];
#pragma unroll
  for (int i = 0; i < 8; i++) acc[i] = cb[d + i];
  float cwv[8][4];
#pragma unroll
  for (int i = 0; i < 8; i++) {
    float4 v = *(const float4*)(cw + (d + i) * 4);
    cwv[i][0] = v.x; cwv[i][1] = v.y; cwv[i][2] = v.z; cwv[i][3] = v.w;
  }
#pragma unroll
  for (int j = 0; j < 4; j++) {
    if (l - 3 + j >= 0) {
      const u16* xr = xgb + (size_t)(bb * XR + l + j) * 4096 + d;
      ushort4 v0 = *(const ushort4*)xr;
      ushort4 v1 = *(const ushort4*)(xr + 4);
      acc[0] += bf2f(v0.x) * cwv[0][j]; acc[1] += bf2f(v0.y) * cwv[1][j];
      acc[2] += bf2f(v0.z) * cwv[2][j]; acc[3] += bf2f(v0.w) * cwv[3][j];
      acc[4] += bf2f(v1.x) * cwv[4][j]; acc[5] += bf2f(v1.y) * cwv[5][j];
      acc[6] += bf2f(v1.z) * cwv[6][j]; acc[7] += bf2f(v1.w) * cwv[7][j];
    }
  }
#pragma unroll
  for (int i = 0; i < 8; i++) row[d + i] = silu_f(acc[i]);
  __syncthreads();
  int wv = t >> 6, lane = t & 63;
  const float4* row4 = (const float4*)row;
  int tk = (bb << 10) + l;
  for (int o = wv; o < 96; o += 4) {
    const float4* wr4 = (const float4*)(w + (size_t)o * DDIM);
    float s0 = 0.f, s1 = 0.f, s2 = 0.f, s3 = 0.f;
#pragma unroll
    for (int k4 = 0; k4 < 8; k4++) {
      int idx = (k4 << 6) + lane;
      float4 wv4 = wr4[idx];
      float4 rv4 = row4[idx];
      s0 += rv4.x * wv4.x; s1 += rv4.y * wv4.y;
      s2 += rv4.z * wv4.z; s3 += rv4.w * wv4.w;
    }
    float s = (s0 + s1) + (s2 + s3);
    s += __shfl_xor(s, 32); s += __shfl_xor(s, 16);
    s += __shfl_xor(s, 8);  s += __shfl_xor(s, 4);
    s += __shfl_xor(s, 2);  s += __shfl_xor(s, 1);
    if (lane == 0) proj[(size_t)tk * 96 + o] = s + b[o];
  }
}

// ---------------- K2b: transpose proj[BL][96] -> projT[96][BL] ----------------
__global__ __launch_bounds__(256) void k_transpose(const float* __restrict__ proj,
                                                   float* __restrict__ projT) {
  __shared__ float tile[64][97];
  int blk = blockIdx.x;                 // 32 blocks: b = blk>>4, 64-token segment = blk&15
  int b = blk >> 4;
  int tok0 = (b << 10) + (blk & 15) * 64;
  int t = threadIdx.x;
  const float* src = proj + (size_t)tok0 * 96;
#pragma unroll
  for (int i = 0; i < 24; i++) {
    int idx = t + i * 256;
    int row = idx / 96, col = idx - row * 96;
    tile[row][col] = src[idx];
  }
  __syncthreads();
  int wv = t >> 6, lane = t & 63;
#pragma unroll
  for (int i = 0; i < 24; i++) {
    int o = wv + i * 4;
    projT[(size_t)o * BL + tok0 + lane] = tile[lane][o];
  }
}

// ---------------- K3: full-sequence selective scan ----------------
// Restructured: lane owns 16 CONSECUTIVE tokens; serial in-register scan within
// lane + ONE 64-lane shuffle scan of lane totals per state (whole 1024-token
// sequence in one shot).  Shuffles/wave: ~600 -> ~30.  P(t)=exp(A*Dl(t)) is
// computed directly from the precomputed delta-prefix, so lane-boundary carries
// need no shuffle.  Division replaced by v_rcp (clip at 1e-10 dominates error,
// reference clips identically).  LDS token arrays use 17-stride padding
// (17 coprime 32 -> 2 lanes/bank = free).
__global__ __launch_bounds__(256) void k_scan(const float* __restrict__ projT,
                                              const u16* __restrict__ xgb,
                                              const float* __restrict__ cw,
                                              const float* __restrict__ cb,
                                              const float* __restrict__ dtw,
                                              const float* __restrict__ dtb,
                                              const float* __restrict__ alog,
                                              const float* __restrict__ dparam,
                                              const float* __restrict__ cs,
                                              u16* __restrict__ yb) {
  __shared__ float dtw_s[64];
  __shared__ float xcp[1088];      // conv+silu x, padded: idx = (tok>>4)*17 + (tok&15)
  __shared__ float dsp[1088];      // delta, padded
  __shared__ float Dlp[1088];      // inclusive delta prefix, padded
  __shared__ float ys4[4][1088];   // per-wave y partials, padded
  __shared__ float wtot[4];
  float* xls = &ys4[0][0];         // 1027 floats; dead before ys4 is written

  int t = threadIdx.x;
  // XCD-aware swizzle: XCD x owns a contiguous 512-wide d range
  int cidx = ((blockIdx.x & 7) << 9) | (blockIdx.x >> 3);   // (b,d)
  int b = cidx >> 11;
  int d = cidx & (DDIM - 1);
  int wv = t >> 6, lane = t & 63;

  if (t < 64) dtw_s[t] = dtw[(size_t)d * 64 + t];
  float4 cwv = *(const float4*)(cw + d * 4);
  float cbv = cb[d];
  float dtbv = dtb[d];
  float Dp = dparam[d];
  const u16* xcol = xgb + (size_t)(b * XR + 3) * 4096 + d;      // x half
  const u16* gcol = xcol + DDIM;                                // gate half
  u16* ycol = yb + ((size_t)(b << 10)) * DDIM + d;
  int colbase = b << 10;

  // ---- stage x column (3-halo) ----
  if (t < 3) xls[t] = 0.f;
#pragma unroll
  for (int k = 0; k < 4; k++) {
    int tok = t + (k << 8);
    xls[3 + tok] = bf2f(xcol[(size_t)tok * 4096]);
  }
  __syncthreads();

  int tok0 = t << 2;   // this thread owns tokens 4t..4t+3 for prep phases
  // ---- conv + silu ----
#pragma unroll
  for (int i = 0; i < 4; i++) {
    int tok = tok0 + i;
    float xc = silu_f(cbv + cwv.x * xls[tok] + cwv.y * xls[tok + 1] +
                      cwv.z * xls[tok + 2] + cwv.w * xls[tok + 3]);
    xcp[((tok >> 4) * 17) + (tok & 15)] = xc;
  }
  // ---- delta = softplus(dt-dot), float4 over 4 consecutive tokens ----
  float d0, d1, d2, d3;
  {
    float4 acc = {dtbv, dtbv, dtbv, dtbv};
    const float* pr = projT + colbase + tok0;
#pragma unroll 8
    for (int kk = 0; kk < 64; kk++) {
      float4 v = *(const float4*)(pr + (size_t)kk * BL);
      float wk = dtw_s[kk];
      acc.x += v.x * wk; acc.y += v.y * wk; acc.z += v.z * wk; acc.w += v.w * wk;
    }
    d0 = (acc.x > 20.f) ? acc.x : log1pf(__expf(acc.x));
    d1 = (acc.y > 20.f) ? acc.y : log1pf(__expf(acc.y));
    d2 = (acc.z > 20.f) ? acc.z : log1pf(__expf(acc.z));
    d3 = (acc.w > 20.f) ? acc.w : log1pf(__expf(acc.w));
    dsp[((tok0 >> 4) * 17) + (tok0 & 15)]           = d0;
    dsp[(((tok0 + 1) >> 4) * 17) + ((tok0 + 1) & 15)] = d1;
    dsp[(((tok0 + 2) >> 4) * 17) + ((tok0 + 2) & 15)] = d2;
    dsp[(((tok0 + 3) >> 4) * 17) + ((tok0 + 3) & 15)] = d3;
  }
  // ---- global inclusive prefix of delta (chunk-serial + one wave scan) ----
  float c0 = d0, c1 = c0 + d1, c2 = c1 + d2, c3 = c2 + d3;
  float sc = c3;
#pragma unroll
  for (int off = 1; off < 64; off <<= 1) {
    float u = __shfl_up(sc, off);
    if (lane >= off) sc += u;
  }
  if (lane == 63) wtot[wv] = sc;
  __syncthreads();
  {
    float base = sc - c3;
#pragma unroll
    for (int i = 0; i < 3; i++) if (i < wv) base += wtot[i];
    Dlp[((tok0 >> 4) * 17) + (tok0 & 15)]             = base + c0;
    Dlp[(((tok0 + 1) >> 4) * 17) + ((tok0 + 1) & 15)] = base + c1;
    Dlp[(((tok0 + 2) >> 4) * 17) + ((tok0 + 2) & 15)] = base + c2;
    Dlp[(((tok0 + 3) >> 4) * 17) + ((tok0 + 3) & 15)] = base + c3;
  }
  __syncthreads();

  // ---- main scan: each wave owns 4 states over the FULL sequence;
  //      lane owns tokens 16*lane .. 16*lane+15 ----
  int pb = lane * 17;
  float uv[16], Dl16[16], y[16];
#pragma unroll
  for (int i = 0; i < 16; i++) {
    uv[i]  = dsp[pb + i] * xcp[pb + i];   // delta * conv_x  (state-independent)
    Dl16[i] = Dlp[pb + i];
    y[i] = 0.f;
  }
  float Dprev = (lane == 0) ? 0.f : Dlp[pb - 2];   // = Dlp[(lane-1)*17 + 15]

#pragma unroll 1
  for (int r = 0; r < 4; r++) {
    int n = (wv << 2) + r;
    float An = -__expf(alog[d * NST + n]);
    float st = cs[(size_t)(b * DDIM + d) * NST + n];
    const float* pB = projT + (size_t)(64 + n) * BL + colbase + (lane << 4);
    float Bv[16];
    *(float4*)(Bv + 0)  = *(const float4*)(pB + 0);
    *(float4*)(Bv + 4)  = *(const float4*)(pB + 4);
    *(float4*)(Bv + 8)  = *(const float4*)(pB + 8);
    *(float4*)(Bv + 12) = *(const float4*)(pB + 12);
    float P[16], w[16];
    float Pp0 = __expf(An * Dprev);
    float Pp = Pp0;
    float wsum = 0.f;
#pragma unroll
    for (int i = 0; i < 16; i++) {
      P[i] = __expf(An * Dl16[i]);
      w[i] = uv[i] * Bv[i] * __builtin_amdgcn_rcpf(fmaxf(Pp, 1e-10f));
      wsum += w[i];
      Pp = P[i];
    }
    // one 64-lane scan of lane totals -> exclusive offset
    float s2 = wsum;
#pragma unroll
    for (int off = 1; off < 64; off <<= 1) {
      float u = __shfl_up(s2, off);
      if (lane >= off) s2 += u;
    }
    float S = s2 - wsum;   // exclusive prefix for this lane
    const float* pC = projT + (size_t)(80 + n) * BL + colbase + (lane << 4);
    float Cv[16];
    *(float4*)(Cv + 0)  = *(const float4*)(pC + 0);
    *(float4*)(Cv + 4)  = *(const float4*)(pC + 4);
    *(float4*)(Cv + 8)  = *(const float4*)(pC + 8);
    *(float4*)(Cv + 12) = *(const float4*)(pC + 12);
    Pp = Pp0;
#pragma unroll
    for (int i = 0; i < 16; i++) {
      S += w[i];
      y[i] += (S * Pp + st * P[i]) * Cv[i];
      Pp = P[i];
    }
  }
  // ---- cross-wave y reduction + D-term + gate + bf16 store ----
#pragma unroll
  for (int i = 0; i < 16; i++) ys4[wv][pb + i] = y[i];
  __syncthreads();
#pragma unroll
  for (int i = 0; i < 4; i++) {
    int tok = tok0 + i;
    int p = ((tok >> 4) * 17) + (tok & 15);
    float yv = ys4[0][p] + ys4[1][p] + ys4[2][p] + ys4[3][p] + xcp[p] * Dp;
    float g = bf2f(gcol[(size_t)tok * 4096]);
    ycol[(size_t)tok * DDIM] = f2bf(yv * silu_f(g));
  }
}

extern "C" void kernel_launch(void* const* d_in, const int* in_sizes, int n_in,
                              void* d_out, int out_size, void* d_ws, size_t ws_size,
                              hipStream_t stream) {
  const float* inp    = (const float*)d_in[0];
  const float* cstate = (const float*)d_in[1];
  const float* norm_w = (const float*)d_in[2];
  const float* w1     = (const float*)d_in[3];
  const float* b1     = (const float*)d_in[4];
  const float* convw  = (const float*)d_in[5];
  const float* convb  = (const float*)d_in[6];
  const float* xpw    = (const float*)d_in[7];
  const float* xpb    = (const float*)d_in[8];
  const float* dtw    = (const float*)d_in[9];
  const float* dtb    = (const float*)d_in[10];
  const float* alog   = (const float*)d_in[11];
  const float* dparam = (const float*)d_in[12];
  const float* wo     = (const float*)d_in[13];
  const float* bo     = (const float*)d_in[14];
  float* out = (float*)d_out;

  // workspace layout, 39,378,944 B total
  char* wsb = (char*)d_ws;
  u16*   w1b    = (u16*)(wsb + 0);            //  8,388,608 B  [4096][1024] bf16
  u16*   wob    = (u16*)(wsb + 8388608);      //  4,194,304 B  [1024][2048] bf16
  float* rscale = (float*)(wsb + 12582912);   //      8,192 B  [2048]
  float* proj   = (float*)(wsb + 12591104);   //    786,432 B  [2048][96] token-major
  float* projT  = (float*)(wsb + 13377536);   //    786,432 B  [96][2048] transposed
  u16*   xgb    = (u16*)(wsb + 14163968);     // 16,826,368 B  [2][1027][4096] bf16
  u16*   yb     = (u16*)(wsb + 30990336);     //  8,388,608 B  [2][1024][2048] bf16

  k_castw<<<4096, 256, 0, stream>>>(w1, w1b);
  k_castw<<<2048, 256, 0, stream>>>(wo, wob);
  k_rowscale<<<BL, 256, 0, stream>>>(inp, rscale);
  k_gemm1_mfma<<<dim3(64, 32), 256, 0, stream>>>(inp, w1b, b1, rscale, norm_w, xgb);
  k_xprojc<<<BL, 256, 0, stream>>>(xgb, convw, convb, xpw, xpb, proj);
  k_transpose<<<32, 256, 0, stream>>>(proj, projT);
  k_scan<<<2 * DDIM, 256, 0, stream>>>(projT, xgb, convw, convb, dtw, dtb,
                                       alog, dparam, cstate, yb);
  k_gemm2_mfma<<<dim3(16, 32), 256, 0, stream>>>(yb, wob, bo, inp, out);
}